// Round 11
// baseline (504.574 us; speedup 1.0000x reference)
//
#include <hip/hip_runtime.h>
#include <stdint.h>

#define NN 50000
#define EE 800000
#define IND 256
#define HD1 512   // layer1 concat width (4 heads x 128)
#define D2C 256   // layer2 width

// ---- two-level CSR sort geometry ----
#define NB1 782                 // buckets per layer (64 nodes each)
#define NB  (2 * NB1)           // 1564 buckets total
#define CH  16384               // edges per binning workgroup
#define WGN ((2 * EE + CH - 1) / CH)   // 98 workgroups
#define TOT (NB * WGN)          // 153272 hist entries
#define SB2 ((TOT + 255) / 256) // 599 scan blocks

// int8 fixed-point codec for h1 (values ~N(0,1); range +-6 never clips in practice)
#define Q_SCALE 21.166666f        // 127/6
#define Q_INV   0.047244094f      // 6/127

typedef float f32x4 __attribute__((ext_vector_type(4)));
typedef __bf16 bf16x8 __attribute__((ext_vector_type(8)));

__device__ inline float bf2f(unsigned int u) {
    union { unsigned int i; float f; } c; c.i = u << 16; return c.f;
}
__device__ inline unsigned int f2bf(float f) {
    union { float f; unsigned int i; } c; c.f = f;
    unsigned int x = c.i;
    return (x + 0x7FFFu + ((x >> 16) & 1u)) >> 16;  // RNE
}
__device__ inline float loadf(const void* p, int idx, int isbf) {
    return isbf ? bf2f(((const unsigned short*)p)[idx]) : ((const float*)p)[idx];
}
// encode float -> int8 byte (round-nearest, clamp +-127)
__device__ inline unsigned int f2q8(float v) {
    float t = fminf(fmaxf(v * Q_SCALE, -127.f), 127.f);
    int q = (int)rintf(t);
    return (unsigned int)q & 0xFFu;
}
// decode 8 int8 bytes -> floats (scale folded into edge weight)
__device__ inline void unpack8_q8(uint2 q, float* o) {
    o[0] = (float)(int)(signed char)(q.x & 0xFFu);
    o[1] = (float)(int)(signed char)((q.x >> 8) & 0xFFu);
    o[2] = (float)(int)(signed char)((q.x >> 16) & 0xFFu);
    o[3] = (float)(int)(signed char)(q.x >> 24);
    o[4] = (float)(int)(signed char)(q.y & 0xFFu);
    o[5] = (float)(int)(signed char)((q.y >> 8) & 0xFFu);
    o[6] = (float)(int)(signed char)((q.y >> 16) & 0xFFu);
    o[7] = (float)(int)(signed char)(q.y >> 24);
}

// ---------------- dtype probe: external float tensors bf16 (flag=1) or fp32 (flag=0)
__global__ void probe_k(const unsigned int* __restrict__ w, int* __restrict__ flag) {
    __shared__ int red[256];
    int t = threadIdx.x;
    int ok = 0;
    for (int i = t; i < 4096; i += 256) {
        unsigned int v = w[i];
        unsigned int e0 = (v >> 7) & 0xffu;
        unsigned int e1 = (v >> 23) & 0xffu;
        ok += (e0 <= 133u) + (e1 <= 133u);
    }
    red[t] = ok;
    __syncthreads();
    for (int s = 128; s > 0; s >>= 1) {
        if (t < s) red[t] += red[t + s];
        __syncthreads();
    }
    if (t == 0) *flag = (red[0] >= 7782) ? 1 : 0;
}

// ---------------- feat -> bf16 (one-time conversion; copy if already bf16)
__global__ __launch_bounds__(256) void convert_k(
    const void* __restrict__ in, const int* __restrict__ flagp,
    unsigned short* __restrict__ out)
{
    int isbf = (*flagp != 0);
    size_t i = ((size_t)blockIdx.x * 256 + threadIdx.x) * 8;
    if (i >= (size_t)NN * IND) return;
    if (isbf) {
        *(uint4*)(out + i) = *(const uint4*)((const unsigned short*)in + i);
    } else {
        const float* f = (const float*)in + i;
        f32x4 p0 = *(const f32x4*)f;
        f32x4 p1 = *(const f32x4*)(f + 4);
        uint4 va;
        va.x = f2bf(p0.x) | (f2bf(p0.y) << 16);
        va.y = f2bf(p0.z) | (f2bf(p0.w) << 16);
        va.z = f2bf(p1.x) | (f2bf(p1.y) << 16);
        va.w = f2bf(p1.z) | (f2bf(p1.w) << 16);
        *(uint4*)(out + i) = va;
    }
}

// ---------------- GEMM, 128x256 tile (A-reuse), fused el/er epilogue.
// C[M,Nc] = A[M,K] * BT[Nc,K]^T. bf16 MFMA, fp32 acc. 4 waves: 2x2 over
// (128 rows x 256 cols); each wave 64x128 = 4x8 frags.
// eler_mode 1: layer1, head = col>>7; el[m*4 + 2*blockIdx.y + hg] direct store.
// eler_mode 2: layer2, Nc=256 single n-block; el[m] = sum of both halves.
__global__ __launch_bounds__(256) void gemm_bt(
    const unsigned short* __restrict__ A, const int* __restrict__ flagp,
    const unsigned short* __restrict__ BT,
    void* __restrict__ C, int c_q8,
    int M, int K, int Nc,
    const void* __restrict__ al, const void* __restrict__ ar,
    float* __restrict__ el, float* __restrict__ er, int eler_mode)
{
    const int LD = 40;
    __shared__ unsigned short Als[128 * LD];
    __shared__ unsigned short Bls[256 * LD];
    __shared__ float elp[256];   // [row][hg]
    __shared__ float erp[256];
    int isbf = (*flagp != 0);
    int tid  = threadIdx.x;
    int wave = tid >> 6;
    int lane = tid & 63;
    int wr = (wave >> 1) * 64;     // 0 or 64
    int wc = (wave & 1) * 128;     // 0 or 128
    int m0 = blockIdx.x * 128;
    int n0 = blockIdx.y * 256;
    elp[tid] = 0.f; erp[tid] = 0.f;
    f32x4 acc[4][8];
#pragma unroll
    for (int i = 0; i < 4; i++)
#pragma unroll
        for (int j = 0; j < 8; j++) acc[i][j] = (f32x4){0.f, 0.f, 0.f, 0.f};
    int sr = tid >> 2;
    int sc = (tid & 3) * 8;
    int frow = lane & 15;
    int kg = (lane >> 4) * 8;
    for (int kt = 0; kt < K; kt += 32) {
#pragma unroll
        for (int half = 0; half < 2; ++half) {
            int r = sr + half * 64;
            int gm = m0 + r;
            uint4 va = make_uint4(0u, 0u, 0u, 0u);
            if (gm < M) va = *(const uint4*)(A + (size_t)gm * K + kt + sc);
            *(uint4*)(Als + r * LD + sc) = va;
        }
#pragma unroll
        for (int q = 0; q < 4; ++q) {
            int r = sr + q * 64;
            uint4 vb = *(const uint4*)(BT + (size_t)(n0 + r) * K + kt + sc);
            *(uint4*)(Bls + r * LD + sc) = vb;
        }
        __syncthreads();
        bf16x8 af[4], bfr[8];
#pragma unroll
        for (int i = 0; i < 4; i++)
            af[i] = __builtin_bit_cast(bf16x8, *(const uint4*)(Als + (wr + i * 16 + frow) * LD + kg));
#pragma unroll
        for (int j = 0; j < 8; j++)
            bfr[j] = __builtin_bit_cast(bf16x8, *(const uint4*)(Bls + (wc + j * 16 + frow) * LD + kg));
#pragma unroll
        for (int i = 0; i < 4; i++)
#pragma unroll
            for (int j = 0; j < 8; j++)
                acc[i][j] = __builtin_amdgcn_mfma_f32_16x16x32_bf16(af[i], bfr[j], acc[i][j], 0, 0, 0);
        __syncthreads();
    }
    // C store. C/D layout: col = lane&15, row = (lane>>4)*4 + reg
    int nb = n0 + wc + frow;
    int mb = m0 + wr + (lane >> 4) * 4;
#pragma unroll
    for (int i = 0; i < 4; i++) {
#pragma unroll
        for (int j = 0; j < 8; j++) {
            int n = nb + j * 16;
#pragma unroll
            for (int r = 0; r < 4; r++) {
                int m = mb + i * 16 + r;
                if (m < M) {
                    if (c_q8)
                        ((unsigned char*)C)[(size_t)m * Nc + n] = (unsigned char)f2q8(acc[i][j][r]);
                    else
                        ((unsigned short*)C)[(size_t)m * Nc + n] = (unsigned short)f2bf(acc[i][j][r]);
                }
            }
        }
    }
    // fused el/er: per-row dot with al/ar over this wave's 128 cols (one head-group)
    float alv[8], arv[8];
#pragma unroll
    for (int j = 0; j < 8; j++) {
        int c = n0 + wc + frow + j * 16;
        alv[j] = loadf(al, c, isbf);
        arv[j] = loadf(ar, c, isbf);
    }
    int hg = wc >> 7;   // 0 or 1
#pragma unroll
    for (int i = 0; i < 4; i++) {
#pragma unroll
        for (int r = 0; r < 4; r++) {
            float pe = 0.f, pr = 0.f;
#pragma unroll
            for (int j = 0; j < 8; j++) {
                pe += acc[i][j][r] * alv[j];
                pr += acc[i][j][r] * arv[j];
            }
#pragma unroll
            for (int o = 1; o < 16; o <<= 1) {
                pe += __shfl_xor(pe, o);
                pr += __shfl_xor(pr, o);
            }
            if ((lane & 15) == 0) {
                int row = wr + (lane >> 4) * 4 + i * 16 + r;
                atomicAdd(&elp[row * 2 + hg], pe);
                atomicAdd(&erp[row * 2 + hg], pr);
            }
        }
    }
    __syncthreads();
    if (tid < 128) {
        int m = m0 + tid;
        if (m < M) {
            if (eler_mode == 1) {
                el[m * 4 + 2 * blockIdx.y + 0] = elp[tid * 2];
                el[m * 4 + 2 * blockIdx.y + 1] = elp[tid * 2 + 1];
                er[m * 4 + 2 * blockIdx.y + 0] = erp[tid * 2];
                er[m * 4 + 2 * blockIdx.y + 1] = erp[tid * 2 + 1];
            } else {
                el[m] = elp[tid * 2] + elp[tid * 2 + 1];
                er[m] = erp[tid * 2] + erp[tid * 2 + 1];
            }
        }
    }
}

// ---------------- transpose external weight [R,C] -> internal bf16 [C,R]
__global__ void transpose_k(const void* __restrict__ in, const int* __restrict__ flagp,
                            unsigned short* __restrict__ out, int R, int C) {
    int isbf = (*flagp != 0);
    int idx = blockIdx.x * blockDim.x + threadIdx.x;
    if (idx < R * C) {
        int i = idx / C, j = idx - i * C;
        unsigned short v = isbf ? ((const unsigned short*)in)[idx]
                                : (unsigned short)f2bf(((const float*)in)[idx]);
        out[j * R + i] = v;
    }
}

// ---------------- deterministic two-level CSR sort ----------------
__global__ __launch_bounds__(256) void binA_k(
    const int* __restrict__ dst1, const int* __restrict__ dst2,
    int* __restrict__ hist)
{
    __shared__ int lh[NB];
    int t = threadIdx.x, w = blockIdx.x;
    for (int b = t; b < NB; b += 256) lh[b] = 0;
    __syncthreads();
    int base = w * CH;
    for (int k = 0; k < CH; k += 256) {
        int i = base + k + t;
        if (i < 2 * EE) {
            int d, lay;
            if (i < EE) { d = dst1[i]; lay = 0; }
            else        { d = dst2[i - EE]; lay = 1; }
            d = ((unsigned)d < (unsigned)NN) ? d : 0;
            atomicAdd(&lh[lay * NB1 + (d >> 6)], 1);
        }
    }
    __syncthreads();
    for (int b = t; b < NB; b += 256) hist[b * WGN + w] = lh[b];
}
__global__ void scan_a(int* __restrict__ hist, int* __restrict__ bsum) {
    __shared__ int sdata[256];
    int t = threadIdx.x;
    int g = blockIdx.x * 256 + t;
    int v = (g < TOT) ? hist[g] : 0;
    sdata[t] = v;
    __syncthreads();
    for (int o = 1; o < 256; o <<= 1) {
        int x = (t >= o) ? sdata[t - o] : 0;
        __syncthreads();
        sdata[t] += x;
        __syncthreads();
    }
    if (g < TOT) hist[g] = sdata[t] - v;
    if (t == 255) bsum[blockIdx.x] = sdata[255];
}
__global__ void scan_b(const int* __restrict__ bsum, int* __restrict__ boff) {
    __shared__ int sdata[1024];
    int t = threadIdx.x;           // 1024 threads
    int v = (t < SB2) ? bsum[t] : 0;
    sdata[t] = v;
    __syncthreads();
    for (int o = 1; o < 1024; o <<= 1) {
        int x = (t >= o) ? sdata[t - o] : 0;
        __syncthreads();
        sdata[t] += x;
        __syncthreads();
    }
    boff[t] = sdata[t] - v;
}
__global__ void scan_c(int* __restrict__ hist, const int* __restrict__ boff) {
    int g = blockIdx.x * 256 + threadIdx.x;
    if (g < TOT) hist[g] += boff[blockIdx.x];
}
__global__ __launch_bounds__(256) void binC_k(
    const int* __restrict__ src1, const int* __restrict__ dst1,
    const int* __restrict__ src2, const int* __restrict__ dst2,
    const int* __restrict__ base_g, unsigned int* __restrict__ bucketed)
{
    __shared__ int cur[NB];
    int t = threadIdx.x, w = blockIdx.x;
    for (int b = t; b < NB; b += 256) cur[b] = base_g[b * WGN + w];
    __syncthreads();
    int base = w * CH;
    for (int k = 0; k < CH; k += 256) {
        int i = base + k + t;
        if (i < 2 * EE) {
            int d, s, lay;
            if (i < EE) { d = dst1[i]; s = src1[i]; lay = 0; }
            else        { d = dst2[i - EE]; s = src2[i - EE]; lay = 1; }
            d = ((unsigned)d < (unsigned)NN) ? d : 0;
            s = ((unsigned)s < (unsigned)NN) ? s : 0;
            int b = lay * NB1 + (d >> 6);
            int p = atomicAdd(&cur[b], 1);
            bucketed[p] = (unsigned)s | ((unsigned)(d & 63) << 16);
        }
    }
}
__global__ __launch_bounds__(256) void binD_k(
    const int* __restrict__ base_g, const unsigned int* __restrict__ bucketed,
    int* __restrict__ csr, int* __restrict__ row_ptr)
{
    __shared__ int cnt[64];
    __shared__ int off[64];
    __shared__ int cur[64];
    int b = blockIdx.x, t = threadIdx.x;
    int s = base_g[b * WGN];
    int e = (b + 1 < NB) ? base_g[(b + 1) * WGN] : (2 * EE);
    int lay = (b >= NB1) ? 1 : 0;
    int b0 = b - lay * NB1;
    if (t < 64) cnt[t] = 0;
    __syncthreads();
    for (int i = s + t; i < e; i += 256)
        atomicAdd(&cnt[bucketed[i] >> 16], 1);
    __syncthreads();
    if (t == 0) {
        int run = s;
        for (int j = 0; j < 64; j++) { off[j] = run; run += cnt[j]; }
    }
    __syncthreads();
    if (t < 64) {
        int node = b0 * 64 + t;
        if (node < NN) row_ptr[lay * NN + node] = off[t];
        cur[t] = off[t];
    }
    __syncthreads();
    for (int i = s + t; i < e; i += 256) {
        unsigned v = bucketed[i];
        int p = atomicAdd(&cur[v >> 16], 1);
        csr[p] = (int)(v & 0xFFFFu);
    }
    if (b == NB - 1 && t == 0) row_ptr[2 * NN] = e;
}

// ---------------- layer1 aggregation: single-pass softmax, int8 h1 gather
// (32-bit offsets; csr guaranteed in-range by binC), fused ELU -> bf16 x2.
__global__ __launch_bounds__(256) void agg1_k(
    const unsigned char* __restrict__ h1,
    const float* __restrict__ el, const float* __restrict__ er,
    const int* __restrict__ row_ptr, const int* __restrict__ csr,
    unsigned short* __restrict__ x2)
{
    int wv = (blockIdx.x * blockDim.x + threadIdx.x) >> 6;
    int lane = threadIdx.x & 63;
    if (wv >= NN) return;
    int h = lane >> 4;
    float erv = er[wv * 4 + h];
    int e0 = row_ptr[wv], e1 = row_ptr[wv + 1];
    unsigned lo = (unsigned)(lane * 8);
    float l = 0.f;
    float acc[8];
#pragma unroll
    for (int j = 0; j < 8; j++) acc[j] = 0.f;
    int e = e0;
    for (; e + 1 < e1; e += 2) {       // two independent gather chains
        int s0 = csr[e];
        int s1 = csr[e + 1];
        float ev0 = el[s0 * 4 + h] + erv;
        float ev1 = el[s1 * 4 + h] + erv;
        ev0 = (ev0 > 0.f) ? ev0 : 0.2f * ev0;
        ev1 = (ev1 > 0.f) ? ev1 : 0.2f * ev1;
        float w0 = __expf(fminf(ev0, 80.f));
        float w1 = __expf(fminf(ev1, 80.f));
        uint2 p0 = *(const uint2*)(h1 + ((unsigned)s0 * HD1 + lo));
        uint2 p1 = *(const uint2*)(h1 + ((unsigned)s1 * HD1 + lo));
        float f0[8], f1[8];
        unpack8_q8(p0, f0);
        unpack8_q8(p1, f1);
        l += w0 + w1;
        float w0s = w0 * Q_INV, w1s = w1 * Q_INV;
#pragma unroll
        for (int j = 0; j < 8; j++) acc[j] += w0s * f0[j] + w1s * f1[j];
    }
    if (e < e1) {
        int s = csr[e];
        float ev = el[s * 4 + h] + erv;
        ev = (ev > 0.f) ? ev : 0.2f * ev;
        float wgt = __expf(fminf(ev, 80.f));
        l += wgt;
        float hf[8];
        unpack8_q8(*(const uint2*)(h1 + ((unsigned)s * HD1 + lo)), hf);
        float ws = wgt * Q_INV;
#pragma unroll
        for (int j = 0; j < 8; j++) acc[j] += ws * hf[j];
    }
    float inv = 1.f / (l + 1e-9f);
    unsigned int o[4];
#pragma unroll
    for (int j = 0; j < 4; j++) {
        float v0 = acc[2 * j] * inv;
        float v1 = acc[2 * j + 1] * inv;
        v0 = (v0 > 0.f) ? v0 : (__expf(v0) - 1.f);   // ELU
        v1 = (v1 > 0.f) ? v1 : (__expf(v1) - 1.f);
        o[j] = f2bf(v0) | (f2bf(v1) << 16);
    }
    *(uint4*)(x2 + (size_t)wv * HD1 + lane * 8) = make_uint4(o[0], o[1], o[2], o[3]);
}

// ---------------- layer2 aggregation -> final output (dtype per flag), h2 bf16
__global__ __launch_bounds__(256) void agg2_k(
    const unsigned short* __restrict__ h2,
    const float* __restrict__ el, const float* __restrict__ er,
    const int* __restrict__ row_ptr, const int* __restrict__ csr,
    void* __restrict__ outv, const int* __restrict__ flagp)
{
    int isbf = (*flagp != 0);
    int wv = (blockIdx.x * blockDim.x + threadIdx.x) >> 6;
    int lane = threadIdx.x & 63;
    if (wv >= NN) return;
    float erv = er[wv];
    int e0 = row_ptr[NN + wv], e1 = row_ptr[NN + wv + 1];
    unsigned lo = (unsigned)(lane * 4);
    float l = 0.f;
    float a0 = 0.f, a1 = 0.f, a2 = 0.f, a3 = 0.f;
    int e = e0;
    for (; e + 1 < e1; e += 2) {
        int s0 = csr[e];
        int s1 = csr[e + 1];
        float ev0 = el[s0] + erv;
        float ev1 = el[s1] + erv;
        ev0 = (ev0 > 0.f) ? ev0 : 0.2f * ev0;
        ev1 = (ev1 > 0.f) ? ev1 : 0.2f * ev1;
        float w0 = __expf(fminf(ev0, 80.f));
        float w1 = __expf(fminf(ev1, 80.f));
        uint2 t0 = *(const uint2*)(h2 + ((unsigned)s0 * D2C + lo));
        uint2 t1 = *(const uint2*)(h2 + ((unsigned)s1 * D2C + lo));
        l += w0 + w1;
        a0 += w0 * bf2f(t0.x & 0xffffu) + w1 * bf2f(t1.x & 0xffffu);
        a1 += w0 * bf2f(t0.x >> 16)     + w1 * bf2f(t1.x >> 16);
        a2 += w0 * bf2f(t0.y & 0xffffu) + w1 * bf2f(t1.y & 0xffffu);
        a3 += w0 * bf2f(t0.y >> 16)     + w1 * bf2f(t1.y >> 16);
    }
    if (e < e1) {
        int s = csr[e];
        float ev = el[s] + erv;
        ev = (ev > 0.f) ? ev : 0.2f * ev;
        float wgt = __expf(fminf(ev, 80.f));
        l += wgt;
        uint2 t = *(const uint2*)(h2 + ((unsigned)s * D2C + lo));
        a0 += wgt * bf2f(t.x & 0xffffu);
        a1 += wgt * bf2f(t.x >> 16);
        a2 += wgt * bf2f(t.y & 0xffffu);
        a3 += wgt * bf2f(t.y >> 16);
    }
    float inv = 1.f / (l + 1e-9f);
    float v0 = a0 * inv, v1 = a1 * inv, v2 = a2 * inv, v3 = a3 * inv;
    if (isbf) {
        uint2 o;
        o.x = f2bf(v0) | (f2bf(v1) << 16);
        o.y = f2bf(v2) | (f2bf(v3) << 16);
        *(uint2*)((unsigned short*)outv + (size_t)wv * D2C + lane * 4) = o;
    } else {
        f32x4 o = (f32x4){v0, v1, v2, v3};
        *(f32x4*)((float*)outv + (size_t)wv * D2C + lane * 4) = o;
    }
}

extern "C" void kernel_launch(void* const* d_in, const int* in_sizes, int n_in,
                              void* d_out, int out_size, void* d_ws, size_t ws_size,
                              hipStream_t stream) {
    const void* feat = d_in[0];
    const int* src1 = (const int*)d_in[1];
    const int* dst1 = (const int*)d_in[2];
    const int* src2 = (const int*)d_in[3];
    const int* dst2 = (const int*)d_in[4];
    const void* W1  = d_in[5];
    const void* al1 = d_in[6];
    const void* ar1 = d_in[7];
    const void* W2  = d_in[8];
    const void* al2 = d_in[9];
    const void* ar2 = d_in[10];

    uint8_t* w = (uint8_t*)d_ws;
    auto alloc = [&](size_t bytes) -> void* {
        void* p = (void*)w;
        w += (bytes + 255) & ~(size_t)255;
        return p;
    };
    int* flag    = (int*)alloc(256);
    float* el    = (float*)alloc((size_t)NN * 4 * 4);
    float* er    = (float*)alloc((size_t)NN * 4 * 4);
    unsigned short* W1T = (unsigned short*)alloc((size_t)IND * HD1 * 2);
    unsigned short* W2T = (unsigned short*)alloc((size_t)HD1 * D2C * 2);
    int* hist    = (int*)alloc((size_t)TOT * 4);
    int* bsum    = (int*)alloc(1024 * 4);
    int* boff    = (int*)alloc(1024 * 4);
    unsigned int* bucketed = (unsigned int*)alloc((size_t)2 * EE * 4);
    int* csr     = (int*)alloc((size_t)2 * EE * 4);
    int* row_ptr = (int*)alloc((size_t)(2 * NN + 1) * 4);
    unsigned char* h1 = (unsigned char*)alloc((size_t)NN * HD1);  // int8: 1 B/elem
    unsigned short* x2 = (unsigned short*)alloc((size_t)NN * HD1 * 2);
    unsigned short* h2 = (unsigned short*)h1;   // bf16 [NN,256] = same footprint
    // featb (bf16 feat) aliases x2: dead after gemm1 reads it, before agg1 writes x2
    unsigned short* featb = x2;

    probe_k<<<1, 256, 0, stream>>>((const unsigned int*)feat, flag);
    convert_k<<<(NN * IND / 8 + 255) / 256, 256, 0, stream>>>(feat, flag, featb);
    transpose_k<<<(IND * HD1 + 255) / 256, 256, 0, stream>>>(W1, flag, W1T, IND, HD1);
    transpose_k<<<(HD1 * D2C + 255) / 256, 256, 0, stream>>>(W2, flag, W2T, HD1, D2C);

    // ---- deterministic two-level CSR build (both layers)
    binA_k<<<WGN, 256, 0, stream>>>(dst1, dst2, hist);
    scan_a<<<SB2, 256, 0, stream>>>(hist, bsum);
    scan_b<<<1, 1024, 0, stream>>>(bsum, boff);
    scan_c<<<SB2, 256, 0, stream>>>(hist, boff);
    binC_k<<<WGN, 256, 0, stream>>>(src1, dst1, src2, dst2, hist, bucketed);
    binD_k<<<NB, 256, 0, stream>>>(hist, bucketed, csr, row_ptr);

    // ---- layer 1 (128x256 tile; fused el/er direct store; h1 stored int8)
    gemm_bt<<<dim3((NN + 127) / 128, HD1 / 256), 256, 0, stream>>>(
        featb, flag, W1T, h1, 1, NN, IND, HD1, al1, ar1, el, er, 1);
    agg1_k<<<(NN + 3) / 4, 256, 0, stream>>>(h1, el, er, row_ptr, csr, x2);

    // ---- layer 2 (single n-block -> el/er direct store, no memsets; h2 bf16)
    gemm_bt<<<dim3((NN + 127) / 128, D2C / 256), 256, 0, stream>>>(
        x2, flag, W2T, (void*)h2, 0, NN, HD1, D2C, al2, ar2, el, er, 2);
    agg2_k<<<(NN + 3) / 4, 256, 0, stream>>>(h2, el, er, row_ptr, csr, d_out, flag);
}

// Round 12
// 454.150 us; speedup vs baseline: 1.1110x; 1.1110x over previous
//
#include <hip/hip_runtime.h>
#include <stdint.h>

#define NN 50000
#define EE 800000
#define IND 256
#define HD1 512   // layer1 concat width (4 heads x 128)
#define D2C 256   // layer2 width

// ---- two-level CSR sort geometry ----
#define NB1 782                 // buckets per layer (64 nodes each)
#define NB  (2 * NB1)           // 1564 buckets total
#define CH  16384               // edges per binning workgroup
#define WGN ((2 * EE + CH - 1) / CH)   // 98 workgroups
#define TOT (NB * WGN)          // 153272 hist entries
#define SB2 ((TOT + 255) / 256) // 599 scan blocks

// int8 fixed-point codec for h1 (values ~N(0,1); range +-6 never clips in practice)
#define Q_SCALE 21.166666f        // 127/6
#define Q_INV   0.047244094f      // 6/127

typedef float f32x4 __attribute__((ext_vector_type(4)));
typedef __bf16 bf16x8 __attribute__((ext_vector_type(8)));

__device__ inline float bf2f(unsigned int u) {
    union { unsigned int i; float f; } c; c.i = u << 16; return c.f;
}
__device__ inline unsigned int f2bf(float f) {
    union { float f; unsigned int i; } c; c.f = f;
    unsigned int x = c.i;
    return (x + 0x7FFFu + ((x >> 16) & 1u)) >> 16;  // RNE
}
__device__ inline float loadf(const void* p, int idx, int isbf) {
    return isbf ? bf2f(((const unsigned short*)p)[idx]) : ((const float*)p)[idx];
}
// encode float -> int8 byte (round-nearest, clamp +-127)
__device__ inline unsigned int f2q8(float v) {
    float t = fminf(fmaxf(v * Q_SCALE, -127.f), 127.f);
    int q = (int)rintf(t);
    return (unsigned int)q & 0xFFu;
}
// decode 8 int8 bytes -> floats (scale folded into edge weight)
__device__ inline void unpack8_q8(uint2 q, float* o) {
    o[0] = (float)(int)(signed char)(q.x & 0xFFu);
    o[1] = (float)(int)(signed char)((q.x >> 8) & 0xFFu);
    o[2] = (float)(int)(signed char)((q.x >> 16) & 0xFFu);
    o[3] = (float)(int)(signed char)(q.x >> 24);
    o[4] = (float)(int)(signed char)(q.y & 0xFFu);
    o[5] = (float)(int)(signed char)((q.y >> 8) & 0xFFu);
    o[6] = (float)(int)(signed char)((q.y >> 16) & 0xFFu);
    o[7] = (float)(int)(signed char)(q.y >> 24);
}
// async global->LDS 16B per lane: dest = lds_base + lane*16 (wave-uniform base)
__device__ inline void glds16(const unsigned short* g, unsigned short* lds_base) {
    __builtin_amdgcn_global_load_lds(
        (const __attribute__((address_space(1))) void*)g,
        (__attribute__((address_space(3))) void*)lds_base, 16, 0, 0);
}

// ---------------- dtype probe: external float tensors bf16 (flag=1) or fp32 (flag=0)
__global__ void probe_k(const unsigned int* __restrict__ w, int* __restrict__ flag) {
    __shared__ int red[256];
    int t = threadIdx.x;
    int ok = 0;
    for (int i = t; i < 4096; i += 256) {
        unsigned int v = w[i];
        unsigned int e0 = (v >> 7) & 0xffu;
        unsigned int e1 = (v >> 23) & 0xffu;
        ok += (e0 <= 133u) + (e1 <= 133u);
    }
    red[t] = ok;
    __syncthreads();
    for (int s = 128; s > 0; s >>= 1) {
        if (t < s) red[t] += red[t + s];
        __syncthreads();
    }
    if (t == 0) *flag = (red[0] >= 7782) ? 1 : 0;
}

// ---------------- feat -> bf16 (one-time conversion; copy if already bf16)
__global__ __launch_bounds__(256) void convert_k(
    const void* __restrict__ in, const int* __restrict__ flagp,
    unsigned short* __restrict__ out)
{
    int isbf = (*flagp != 0);
    size_t i = ((size_t)blockIdx.x * 256 + threadIdx.x) * 8;
    if (i >= (size_t)NN * IND) return;
    if (isbf) {
        *(uint4*)(out + i) = *(const uint4*)((const unsigned short*)in + i);
    } else {
        const float* f = (const float*)in + i;
        f32x4 p0 = *(const f32x4*)f;
        f32x4 p1 = *(const f32x4*)(f + 4);
        uint4 va;
        va.x = f2bf(p0.x) | (f2bf(p0.y) << 16);
        va.y = f2bf(p0.z) | (f2bf(p0.w) << 16);
        va.z = f2bf(p1.x) | (f2bf(p1.y) << 16);
        va.w = f2bf(p1.z) | (f2bf(p1.w) << 16);
        *(uint4*)(out + i) = va;
    }
}

// ---------------- GEMM 128x128 tile with async global->LDS staging.
// C[M,Nc] = A[M,K] * BT[Nc,K]^T. bf16 MFMA, fp32 acc. LD=32 (unpadded —
// required by global_load_lds lane-contiguity; bank conflicts accepted per m97).
// eler_mode 1: n-block == one head, el[m*4+blockIdx.y] direct store (layer1).
// eler_mode 2: el[m] += partial via atomicAdd (layer2; el/er pre-zeroed).
__global__ __launch_bounds__(256) void gemm_bt(
    const unsigned short* __restrict__ A, const int* __restrict__ flagp,
    const unsigned short* __restrict__ BT,
    void* __restrict__ C, int c_q8,
    int M, int K, int Nc,
    const void* __restrict__ al, const void* __restrict__ ar,
    float* __restrict__ el, float* __restrict__ er, int eler_mode)
{
    __shared__ unsigned short Als[128 * 32];
    __shared__ unsigned short Bls[128 * 32];
    __shared__ float elp[128];
    __shared__ float erp[128];
    int isbf = (*flagp != 0);
    int tid  = threadIdx.x;
    int wave = tid >> 6;
    int lane = tid & 63;
    int wr = (wave >> 1) * 64;
    int wc = (wave & 1) * 64;
    int m0 = blockIdx.x * 128;
    int n0 = blockIdx.y * 128;
    if (tid < 128) { elp[tid] = 0.f; erp[tid] = 0.f; }
    f32x4 acc[4][4];
#pragma unroll
    for (int i = 0; i < 4; i++)
#pragma unroll
        for (int j = 0; j < 4; j++) acc[i][j] = (f32x4){0.f, 0.f, 0.f, 0.f};
    int frow = lane & 15;
    int kg = (lane >> 4) * 8;
    // staging geometry: chunk = 16 rows (1 KB); lane i -> row i>>2, col (i&3)*8
    int srow = lane >> 2;
    int scol = (lane & 3) * 8;
    for (int kt = 0; kt < K; kt += 32) {
#pragma unroll
        for (int q = 0; q < 2; ++q) {
            int chunk = wave + q * 4;            // 0..7
            int r = chunk * 16 + srow;
            int gm = m0 + r; if (gm >= M) gm = M - 1;   // clamp: dup reads, unused rows
            glds16(A + (size_t)gm * K + kt + scol, Als + chunk * 512);
            glds16(BT + (size_t)(n0 + r) * K + kt + scol, Bls + chunk * 512);
        }
        __syncthreads();
        bf16x8 af[4], bfr[4];
#pragma unroll
        for (int i = 0; i < 4; i++)
            af[i] = __builtin_bit_cast(bf16x8, *(const uint4*)(Als + (wr + i * 16 + frow) * 32 + kg));
#pragma unroll
        for (int j = 0; j < 4; j++)
            bfr[j] = __builtin_bit_cast(bf16x8, *(const uint4*)(Bls + (wc + j * 16 + frow) * 32 + kg));
#pragma unroll
        for (int i = 0; i < 4; i++)
#pragma unroll
            for (int j = 0; j < 4; j++)
                acc[i][j] = __builtin_amdgcn_mfma_f32_16x16x32_bf16(af[i], bfr[j], acc[i][j], 0, 0, 0);
        __syncthreads();
    }
    // C store. C/D layout: col = lane&15, row = (lane>>4)*4 + reg
    int nb = n0 + wc + frow;
    int mb = m0 + wr + (lane >> 4) * 4;
#pragma unroll
    for (int i = 0; i < 4; i++) {
#pragma unroll
        for (int j = 0; j < 4; j++) {
            int n = nb + j * 16;
#pragma unroll
            for (int r = 0; r < 4; r++) {
                int m = mb + i * 16 + r;
                if (m < M) {
                    if (c_q8)
                        ((unsigned char*)C)[(size_t)m * Nc + n] = (unsigned char)f2q8(acc[i][j][r]);
                    else
                        ((unsigned short*)C)[(size_t)m * Nc + n] = (unsigned short)f2bf(acc[i][j][r]);
                }
            }
        }
    }
    // fused el/er: per-row dot with al/ar over this block's 128 cols
    float alv[4], arv[4];
#pragma unroll
    for (int j = 0; j < 4; j++) {
        int c = n0 + wc + frow + j * 16;
        alv[j] = loadf(al, c, isbf);
        arv[j] = loadf(ar, c, isbf);
    }
#pragma unroll
    for (int i = 0; i < 4; i++) {
#pragma unroll
        for (int r = 0; r < 4; r++) {
            float pe = 0.f, pr = 0.f;
#pragma unroll
            for (int j = 0; j < 4; j++) {
                pe += acc[i][j][r] * alv[j];
                pr += acc[i][j][r] * arv[j];
            }
#pragma unroll
            for (int o = 1; o < 16; o <<= 1) {
                pe += __shfl_xor(pe, o);
                pr += __shfl_xor(pr, o);
            }
            if ((lane & 15) == 0) {
                int row = wr + (lane >> 4) * 4 + i * 16 + r;
                atomicAdd(&elp[row], pe);
                atomicAdd(&erp[row], pr);
            }
        }
    }
    __syncthreads();
    if (tid < 128) {
        int m = m0 + tid;
        if (m < M) {
            if (eler_mode == 1) {
                el[m * 4 + blockIdx.y] = elp[tid];
                er[m * 4 + blockIdx.y] = erp[tid];
            } else {
                atomicAdd(&el[m], elp[tid]);
                atomicAdd(&er[m], erp[tid]);
            }
        }
    }
}

// ---------------- transpose external weight [R,C] -> internal bf16 [C,R]
__global__ void transpose_k(const void* __restrict__ in, const int* __restrict__ flagp,
                            unsigned short* __restrict__ out, int R, int C) {
    int isbf = (*flagp != 0);
    int idx = blockIdx.x * blockDim.x + threadIdx.x;
    if (idx < R * C) {
        int i = idx / C, j = idx - i * C;
        unsigned short v = isbf ? ((const unsigned short*)in)[idx]
                                : (unsigned short)f2bf(((const float*)in)[idx]);
        out[j * R + i] = v;
    }
}

// ---------------- deterministic two-level CSR sort ----------------
__global__ __launch_bounds__(256) void binA_k(
    const int* __restrict__ dst1, const int* __restrict__ dst2,
    int* __restrict__ hist)
{
    __shared__ int lh[NB];
    int t = threadIdx.x, w = blockIdx.x;
    for (int b = t; b < NB; b += 256) lh[b] = 0;
    __syncthreads();
    int base = w * CH;
    for (int k = 0; k < CH; k += 256) {
        int i = base + k + t;
        if (i < 2 * EE) {
            int d, lay;
            if (i < EE) { d = dst1[i]; lay = 0; }
            else        { d = dst2[i - EE]; lay = 1; }
            d = ((unsigned)d < (unsigned)NN) ? d : 0;
            atomicAdd(&lh[lay * NB1 + (d >> 6)], 1);
        }
    }
    __syncthreads();
    for (int b = t; b < NB; b += 256) hist[b * WGN + w] = lh[b];
}
__global__ void scan_a(int* __restrict__ hist, int* __restrict__ bsum) {
    __shared__ int sdata[256];
    int t = threadIdx.x;
    int g = blockIdx.x * 256 + t;
    int v = (g < TOT) ? hist[g] : 0;
    sdata[t] = v;
    __syncthreads();
    for (int o = 1; o < 256; o <<= 1) {
        int x = (t >= o) ? sdata[t - o] : 0;
        __syncthreads();
        sdata[t] += x;
        __syncthreads();
    }
    if (g < TOT) hist[g] = sdata[t] - v;
    if (t == 255) bsum[blockIdx.x] = sdata[255];
}
__global__ void scan_b(const int* __restrict__ bsum, int* __restrict__ boff) {
    __shared__ int sdata[1024];
    int t = threadIdx.x;           // 1024 threads
    int v = (t < SB2) ? bsum[t] : 0;
    sdata[t] = v;
    __syncthreads();
    for (int o = 1; o < 1024; o <<= 1) {
        int x = (t >= o) ? sdata[t - o] : 0;
        __syncthreads();
        sdata[t] += x;
        __syncthreads();
    }
    boff[t] = sdata[t] - v;
}
__global__ void scan_c(int* __restrict__ hist, const int* __restrict__ boff) {
    int g = blockIdx.x * 256 + threadIdx.x;
    if (g < TOT) hist[g] += boff[blockIdx.x];
}
__global__ __launch_bounds__(256) void binC_k(
    const int* __restrict__ src1, const int* __restrict__ dst1,
    const int* __restrict__ src2, const int* __restrict__ dst2,
    const int* __restrict__ base_g, unsigned int* __restrict__ bucketed)
{
    __shared__ int cur[NB];
    int t = threadIdx.x, w = blockIdx.x;
    for (int b = t; b < NB; b += 256) cur[b] = base_g[b * WGN + w];
    __syncthreads();
    int base = w * CH;
    for (int k = 0; k < CH; k += 256) {
        int i = base + k + t;
        if (i < 2 * EE) {
            int d, s, lay;
            if (i < EE) { d = dst1[i]; s = src1[i]; lay = 0; }
            else        { d = dst2[i - EE]; s = src2[i - EE]; lay = 1; }
            d = ((unsigned)d < (unsigned)NN) ? d : 0;
            s = ((unsigned)s < (unsigned)NN) ? s : 0;
            int b = lay * NB1 + (d >> 6);
            int p = atomicAdd(&cur[b], 1);
            bucketed[p] = (unsigned)s | ((unsigned)(d & 63) << 16);
        }
    }
}
__global__ __launch_bounds__(256) void binD_k(
    const int* __restrict__ base_g, const unsigned int* __restrict__ bucketed,
    int* __restrict__ csr, int* __restrict__ row_ptr)
{
    __shared__ int cnt[64];
    __shared__ int off[64];
    __shared__ int cur[64];
    int b = blockIdx.x, t = threadIdx.x;
    int s = base_g[b * WGN];
    int e = (b + 1 < NB) ? base_g[(b + 1) * WGN] : (2 * EE);
    int lay = (b >= NB1) ? 1 : 0;
    int b0 = b - lay * NB1;
    if (t < 64) cnt[t] = 0;
    __syncthreads();
    for (int i = s + t; i < e; i += 256)
        atomicAdd(&cnt[bucketed[i] >> 16], 1);
    __syncthreads();
    if (t == 0) {
        int run = s;
        for (int j = 0; j < 64; j++) { off[j] = run; run += cnt[j]; }
    }
    __syncthreads();
    if (t < 64) {
        int node = b0 * 64 + t;
        if (node < NN) row_ptr[lay * NN + node] = off[t];
        cur[t] = off[t];
    }
    __syncthreads();
    for (int i = s + t; i < e; i += 256) {
        unsigned v = bucketed[i];
        int p = atomicAdd(&cur[v >> 16], 1);
        csr[p] = (int)(v & 0xFFFFu);
    }
    if (b == NB - 1 && t == 0) row_ptr[2 * NN] = e;
}

// ---------------- layer1 aggregation: single-pass softmax, int8 h1 gather,
// fused ELU -> bf16 x2. (r10-exact: clamps + size_t addressing kept — r11's
// "trim" of these regressed 79.5->89.9 us.)
__global__ __launch_bounds__(256) void agg1_k(
    const unsigned char* __restrict__ h1,
    const float* __restrict__ el, const float* __restrict__ er,
    const int* __restrict__ row_ptr, const int* __restrict__ csr,
    unsigned short* __restrict__ x2)
{
    int wv = (blockIdx.x * blockDim.x + threadIdx.x) >> 6;
    int lane = threadIdx.x & 63;
    if (wv >= NN) return;
    int h = lane >> 4;
    float erv = er[wv * 4 + h];
    int e0 = row_ptr[wv], e1 = row_ptr[wv + 1];
    float l = 0.f;
    float acc[8];
#pragma unroll
    for (int j = 0; j < 8; j++) acc[j] = 0.f;
    int e = e0;
    for (; e + 1 < e1; e += 2) {       // two independent gather chains
        int s0 = csr[e];
        int s1 = csr[e + 1];
        s0 = ((unsigned)s0 < (unsigned)NN) ? s0 : 0;
        s1 = ((unsigned)s1 < (unsigned)NN) ? s1 : 0;
        float ev0 = el[s0 * 4 + h] + erv;
        float ev1 = el[s1 * 4 + h] + erv;
        ev0 = (ev0 > 0.f) ? ev0 : 0.2f * ev0;
        ev1 = (ev1 > 0.f) ? ev1 : 0.2f * ev1;
        float w0 = __expf(fminf(ev0, 80.f));
        float w1 = __expf(fminf(ev1, 80.f));
        uint2 p0 = *(const uint2*)(h1 + (size_t)s0 * HD1 + lane * 8);
        uint2 p1 = *(const uint2*)(h1 + (size_t)s1 * HD1 + lane * 8);
        float f0[8], f1[8];
        unpack8_q8(p0, f0);
        unpack8_q8(p1, f1);
        l += w0 + w1;
        float w0s = w0 * Q_INV, w1s = w1 * Q_INV;
#pragma unroll
        for (int j = 0; j < 8; j++) acc[j] += w0s * f0[j] + w1s * f1[j];
    }
    if (e < e1) {
        int s = csr[e];
        s = ((unsigned)s < (unsigned)NN) ? s : 0;
        float ev = el[s * 4 + h] + erv;
        ev = (ev > 0.f) ? ev : 0.2f * ev;
        float wgt = __expf(fminf(ev, 80.f));
        l += wgt;
        float hf[8];
        unpack8_q8(*(const uint2*)(h1 + (size_t)s * HD1 + lane * 8), hf);
        float ws = wgt * Q_INV;
#pragma unroll
        for (int j = 0; j < 8; j++) acc[j] += ws * hf[j];
    }
    float inv = 1.f / (l + 1e-9f);
    unsigned int o[4];
#pragma unroll
    for (int j = 0; j < 4; j++) {
        float v0 = acc[2 * j] * inv;
        float v1 = acc[2 * j + 1] * inv;
        v0 = (v0 > 0.f) ? v0 : (__expf(v0) - 1.f);   // ELU
        v1 = (v1 > 0.f) ? v1 : (__expf(v1) - 1.f);
        o[j] = f2bf(v0) | (f2bf(v1) << 16);
    }
    *(uint4*)(x2 + (size_t)wv * HD1 + lane * 8) = make_uint4(o[0], o[1], o[2], o[3]);
}

// ---------------- layer2 aggregation -> final output (dtype per flag), h2 bf16
__global__ __launch_bounds__(256) void agg2_k(
    const unsigned short* __restrict__ h2,
    const float* __restrict__ el, const float* __restrict__ er,
    const int* __restrict__ row_ptr, const int* __restrict__ csr,
    void* __restrict__ outv, const int* __restrict__ flagp)
{
    int isbf = (*flagp != 0);
    int wv = (blockIdx.x * blockDim.x + threadIdx.x) >> 6;
    int lane = threadIdx.x & 63;
    if (wv >= NN) return;
    float erv = er[wv];
    int e0 = row_ptr[NN + wv], e1 = row_ptr[NN + wv + 1];
    float l = 0.f;
    float a0 = 0.f, a1 = 0.f, a2 = 0.f, a3 = 0.f;
    int e = e0;
    for (; e + 1 < e1; e += 2) {
        int s0 = csr[e];
        int s1 = csr[e + 1];
        s0 = ((unsigned)s0 < (unsigned)NN) ? s0 : 0;
        s1 = ((unsigned)s1 < (unsigned)NN) ? s1 : 0;
        float ev0 = el[s0] + erv;
        float ev1 = el[s1] + erv;
        ev0 = (ev0 > 0.f) ? ev0 : 0.2f * ev0;
        ev1 = (ev1 > 0.f) ? ev1 : 0.2f * ev1;
        float w0 = __expf(fminf(ev0, 80.f));
        float w1 = __expf(fminf(ev1, 80.f));
        uint2 t0 = *(const uint2*)(h2 + (size_t)s0 * D2C + lane * 4);
        uint2 t1 = *(const uint2*)(h2 + (size_t)s1 * D2C + lane * 4);
        l += w0 + w1;
        a0 += w0 * bf2f(t0.x & 0xffffu) + w1 * bf2f(t1.x & 0xffffu);
        a1 += w0 * bf2f(t0.x >> 16)     + w1 * bf2f(t1.x >> 16);
        a2 += w0 * bf2f(t0.y & 0xffffu) + w1 * bf2f(t1.y & 0xffffu);
        a3 += w0 * bf2f(t0.y >> 16)     + w1 * bf2f(t1.y >> 16);
    }
    if (e < e1) {
        int s = csr[e];
        s = ((unsigned)s < (unsigned)NN) ? s : 0;
        float ev = el[s] + erv;
        ev = (ev > 0.f) ? ev : 0.2f * ev;
        float wgt = __expf(fminf(ev, 80.f));
        l += wgt;
        uint2 t = *(const uint2*)(h2 + (size_t)s * D2C + lane * 4);
        a0 += wgt * bf2f(t.x & 0xffffu);
        a1 += wgt * bf2f(t.x >> 16);
        a2 += wgt * bf2f(t.y & 0xffffu);
        a3 += wgt * bf2f(t.y >> 16);
    }
    float inv = 1.f / (l + 1e-9f);
    float v0 = a0 * inv, v1 = a1 * inv, v2 = a2 * inv, v3 = a3 * inv;
    if (isbf) {
        uint2 o;
        o.x = f2bf(v0) | (f2bf(v1) << 16);
        o.y = f2bf(v2) | (f2bf(v3) << 16);
        *(uint2*)((unsigned short*)outv + (size_t)wv * D2C + lane * 4) = o;
    } else {
        f32x4 o = (f32x4){v0, v1, v2, v3};
        *(f32x4*)((float*)outv + (size_t)wv * D2C + lane * 4) = o;
    }
}

extern "C" void kernel_launch(void* const* d_in, const int* in_sizes, int n_in,
                              void* d_out, int out_size, void* d_ws, size_t ws_size,
                              hipStream_t stream) {
    const void* feat = d_in[0];
    const int* src1 = (const int*)d_in[1];
    const int* dst1 = (const int*)d_in[2];
    const int* src2 = (const int*)d_in[3];
    const int* dst2 = (const int*)d_in[4];
    const void* W1  = d_in[5];
    const void* al1 = d_in[6];
    const void* ar1 = d_in[7];
    const void* W2  = d_in[8];
    const void* al2 = d_in[9];
    const void* ar2 = d_in[10];

    uint8_t* w = (uint8_t*)d_ws;
    auto alloc = [&](size_t bytes) -> void* {
        void* p = (void*)w;
        w += (bytes + 255) & ~(size_t)255;
        return p;
    };
    int* flag    = (int*)alloc(256);
    float* el    = (float*)alloc((size_t)NN * 4 * 4);
    float* er    = (float*)alloc((size_t)NN * 4 * 4);
    unsigned short* W1T = (unsigned short*)alloc((size_t)IND * HD1 * 2);
    unsigned short* W2T = (unsigned short*)alloc((size_t)HD1 * D2C * 2);
    int* hist    = (int*)alloc((size_t)TOT * 4);
    int* bsum    = (int*)alloc(1024 * 4);
    int* boff    = (int*)alloc(1024 * 4);
    unsigned int* bucketed = (unsigned int*)alloc((size_t)2 * EE * 4);
    int* csr     = (int*)alloc((size_t)2 * EE * 4);
    int* row_ptr = (int*)alloc((size_t)(2 * NN + 1) * 4);
    unsigned char* h1 = (unsigned char*)alloc((size_t)NN * HD1);  // int8: 1 B/elem
    unsigned short* x2 = (unsigned short*)alloc((size_t)NN * HD1 * 2);
    unsigned short* h2 = (unsigned short*)h1;   // bf16 [NN,256] = same footprint
    // featb (bf16 feat) aliases x2: dead after gemm1 reads it, before agg1 writes x2
    unsigned short* featb = x2;

    probe_k<<<1, 256, 0, stream>>>((const unsigned int*)feat, flag);
    convert_k<<<(NN * IND / 8 + 255) / 256, 256, 0, stream>>>(feat, flag, featb);
    transpose_k<<<(IND * HD1 + 255) / 256, 256, 0, stream>>>(W1, flag, W1T, IND, HD1);
    transpose_k<<<(HD1 * D2C + 255) / 256, 256, 0, stream>>>(W2, flag, W2T, HD1, D2C);

    // ---- deterministic two-level CSR build (both layers)
    binA_k<<<WGN, 256, 0, stream>>>(dst1, dst2, hist);
    scan_a<<<SB2, 256, 0, stream>>>(hist, bsum);
    scan_b<<<1, 1024, 0, stream>>>(bsum, boff);
    scan_c<<<SB2, 256, 0, stream>>>(hist, boff);
    binC_k<<<WGN, 256, 0, stream>>>(src1, dst1, src2, dst2, hist, bucketed);
    binD_k<<<NB, 256, 0, stream>>>(hist, bucketed, csr, row_ptr);

    // ---- layer 1 (glds-staged GEMM; fused el/er direct store; h1 stored int8)
    gemm_bt<<<dim3((NN + 127) / 128, HD1 / 128), 256, 0, stream>>>(
        featb, flag, W1T, h1, 1, NN, IND, HD1, al1, ar1, el, er, 1);
    agg1_k<<<(NN + 3) / 4, 256, 0, stream>>>(h1, el, er, row_ptr, csr, x2);

    // ---- layer 2 (fused el/er via atomics; zero first; h2 bf16)
    hipMemsetAsync(el, 0, (size_t)NN * 4, stream);
    hipMemsetAsync(er, 0, (size_t)NN * 4, stream);
    gemm_bt<<<dim3((NN + 127) / 128, D2C / 128), 256, 0, stream>>>(
        x2, flag, W2T, (void*)h2, 0, NN, HD1, D2C, al2, ar2, el, er, 2);
    agg2_k<<<(NN + 3) / 4, 256, 0, stream>>>(h2, el, er, row_ptr, csr, d_out, flag);
}